// Round 9
// baseline (128.497 us; speedup 1.0000x reference)
//
#include <hip/hip_runtime.h>
#include <hip/hip_bf16.h>

#define NDIM 128
#define BDIM 131072
#define NMZI 8128                       // 128*127/2
#define NCHUNK 16
#define CSTEP (NMZI / NCHUNK)           // 508 steps per chunk
#define NJG 8                           // j-groups per block (scan groups)
#define NCOL 32                         // columns per block
#define NLOC 16                         // max local scan length
static constexpr float CC = 0.70710678118654752440f;  // sqrt(0.5)

typedef __attribute__((ext_vector_type(8))) short bf16x8;
typedef __attribute__((ext_vector_type(4))) float f32x4;

// Static device scratch (d_ws size unknown -> don't touch it)
__device__ __align__(16) float2         g_V[NCHUNK * NDIM * NDIM];  // chunk partial unitaries (2 MB)
__device__ __align__(16) float2         g_W8[8 * NDIM * NDIM];      // compose level 0 out
__device__ __align__(16) float2         g_W4[4 * NDIM * NDIM];      // compose level 1 out
__device__ __align__(16) float2         g_Y[2 * NDIM * NDIM];       // compose level 2 out
// Packed K=256 table for real-output GEMM: kg2<16 -> Ur[k=kg2*8+e][n]; kg2>=16 -> -Ui
__device__ __align__(16) unsigned short g_TB[32 * NDIM * 8];        // 64 KB
// Separate tables for the (unlikely) complex-interleaved output mode
__device__ __align__(16) unsigned short g_Ur[16 * NDIM * 8];
__device__ __align__(16) unsigned short g_Ui[16 * NDIM * 8];

__device__ inline unsigned short f2bf(float f) {
    union { __hip_bfloat16 h; unsigned short u; } cv;
    cv.h = __float2bfloat16(f);
    return cv.u;
}

// ---------------- K2: build chunk partial unitaries (affine-scan) ----------------
// grid (4 col-slabs, NCHUNK=16) x 256 threads. 508 rotations per chunk.
__global__ __launch_bounds__(256) void build_scan(const float* __restrict__ mzi) {
    __shared__ float2 Usm[NDIM][NCOL];        // 32 KB
    __shared__ float4 phs[CSTEP];             // 8.1 KB
    __shared__ float4 comp[NJG][NCOL];        // 4 KB
    const int tid   = threadIdx.x;
    const int c     = tid & 31;
    const int g     = tid >> 5;
    const int col0  = blockIdx.x * NCOL;
    const int chunk = blockIdx.y;
    const int s0 = chunk * CSTEP, s1 = s0 + CSTEP;

    for (int k = g; k < NDIM; k += NJG)
        Usm[k][c] = make_float2((k == col0 + c) ? 1.f : 0.f, 0.f);
    const float2* mzp = (const float2*)mzi;   // (theta, phi) pairs
    for (int t = tid; t < CSTEP; t += 256) {
        const float2 mz = mzp[s0 + t];
        float sp, cp, st, ct;
        sincosf(mz.y, &sp, &cp);              // phi
        sincosf(mz.x, &st, &ct);              // theta
        phs[t] = make_float4(cp, sp, CC * ct, CC * st);
    }
    __syncthreads();

    int i = 0, base = 0;
    while (base + (NDIM - 1 - i) <= s0) { base += NDIM - 1 - i; ++i; }

    int s = s0;
    while (s < s1) {
        const int cnt  = NDIM - 1 - i;
        const int jA   = i + 1 + (s - base);
        const int L    = min(s1, base + cnt) - s;
        const int nloc = (L + NJG - 1) >> 3;
        const int myBeg = g * nloc;
        const int myN   = max(0, min(nloc, L - myBeg));
        const int pbase = s - s0;

        const float2 r0 = Usm[i][c];          // read BEFORE barrier

        float2 treg[NLOC];
        float2 qth[NLOC];
        float  A = 1.f;
        float2 Bc = make_float2(0.f, 0.f);
        #pragma unroll
        for (int kk = 0; kk < NLOC; ++kk) {
            if (kk < myN) {
                const int off = myBeg + kk;
                const float4 q  = phs[pbase + off];
                const float2 rj = Usm[jA + off][c];
                const float tr = fmaf(q.x, rj.x, -q.y * rj.y);
                const float ti = fmaf(q.x, rj.y,  q.y * rj.x);
                treg[kk] = make_float2(tr, ti);
                qth[kk]  = make_float2(q.z, q.w);
                Bc.x = CC * (Bc.x + tr);
                Bc.y = CC * (Bc.y + ti);
                A *= CC;
            }
        }
        comp[g][c] = make_float4(A, Bc.x, Bc.y, 0.f);
        __syncthreads();

        float2 r = r0;
        for (int h = 0; h < g; ++h) {
            const float4 cm = comp[h][c];
            r.x = fmaf(cm.x, r.x, cm.y);
            r.y = fmaf(cm.x, r.y, cm.z);
        }

        #pragma unroll
        for (int kk = 0; kk < NLOC; ++kk) {
            if (kk < myN) {
                const float2 t = treg[kk];
                const float2 q = qth[kk];
                const float dr = r.x - t.x, di = r.y - t.y;
                const float njx = fmaf(q.x, dr, -q.y * di);
                const float njy = fmaf(q.x, di,  q.y * dr);
                Usm[jA + myBeg + kk][c] = make_float2(njx, njy);
                r.x = CC * (r.x + t.x);
                r.y = CC * (r.y + t.y);
            }
        }
        if (myN > 0 && (myBeg + myN == L))
            Usm[i][c] = r;
        __syncthreads();

        s += L;
        if (s == base + cnt) { base += cnt; ++i; }
    }

    float2* Vp = g_V + chunk * NDIM * NDIM;
    for (int k = g; k < NDIM; k += NJG)
        Vp[k * NDIM + col0 + c] = Usm[k][c];
}

// ---------------- K3: compose tree level ----------------
// level 0: W8[p] = V[2p+1]*V[2p],  p<8
// level 1: W4[q] = W8[2q+1]*W8[2q], q<4
// level 2: Y[r]  = W4[2r+1]*W4[2r], r<2
__global__ __launch_bounds__(128) void compose(int level) {
    const int p = blockIdx.y, n = blockIdx.x, m = threadIdx.x;
    const float2* A; const float2* B; float2* Cout;
    if (level == 0) {
        A = g_V + (2 * p + 1) * NDIM * NDIM;
        B = g_V + (2 * p) * NDIM * NDIM;
        Cout = g_W8 + p * NDIM * NDIM;
    } else if (level == 1) {
        A = g_W8 + (2 * p + 1) * NDIM * NDIM;
        B = g_W8 + (2 * p) * NDIM * NDIM;
        Cout = g_W4 + p * NDIM * NDIM;
    } else {
        A = g_W4 + (2 * p + 1) * NDIM * NDIM;
        B = g_W4 + (2 * p) * NDIM * NDIM;
        Cout = g_Y + p * NDIM * NDIM;
    }
    __shared__ float2 arow[NDIM];
    arow[m] = A[n * NDIM + m];
    __syncthreads();
    float cr = 0.f, ci = 0.f;
    #pragma unroll 8
    for (int k = 0; k < NDIM; ++k) {
        const float2 b = B[k * NDIM + m];
        const float2 a = arow[k];
        cr = fmaf(a.x, b.x, fmaf(-a.y, b.y, cr));
        ci = fmaf(a.x, b.y, fmaf( a.y, b.x, ci));
    }
    Cout[n * NDIM + m] = make_float2(cr, ci);
}

// ---------------- K4: final compose U = Y1*Y0, diag, emit packed bf16 ----------------
__global__ __launch_bounds__(128) void compose_final(const float* __restrict__ oph) {
    const int n = blockIdx.x, m = threadIdx.x;
    const float2* A = g_Y + NDIM * NDIM;   // Y1 (left)
    const float2* B = g_Y;                 // Y0 (right)
    __shared__ float2 arow[NDIM];
    arow[m] = A[n * NDIM + m];
    __syncthreads();
    float cr = 0.f, ci = 0.f;
    #pragma unroll 8
    for (int k = 0; k < NDIM; ++k) {
        const float2 b = B[k * NDIM + m];
        const float2 a = arow[k];
        cr = fmaf(a.x, b.x, fmaf(-a.y, b.y, cr));
        ci = fmaf(a.x, b.y, fmaf( a.y, b.x, ci));
    }
    float ds, dc;
    sincosf(oph[n], &ds, &dc);
    const float vr = fmaf(cr, dc, -ci * ds);
    const float vi = fmaf(cr, ds,  ci * dc);
    const int kg = m >> 3, e = m & 7;
    g_TB[(kg * NDIM + n) * 8 + e]        = f2bf(vr);
    g_TB[((16 + kg) * NDIM + n) * 8 + e] = f2bf(-vi);
    g_Ur[(kg * NDIM + n) * 8 + e] = f2bf(vr);
    g_Ui[(kg * NDIM + n) * 8 + e] = f2bf(vi);
}

// ---------------- K5a: real-output GEMM (out_size == B*N, f32 real part) ----------------
// Identical structure to R8 (verified absmax 0.03125) EXCEPT: x loads and
// out stores are NONTEMPORAL (buffer `nt`) to bypass Infinity-Cache
// retention — tests the "L3-path ~2 TB/s is the wall" theory. Table reads
// stay cached (64 KB, L2-resident).
__global__ __launch_bounds__(256) void cmatmul0(const float* __restrict__ xr,
                                                const float* __restrict__ xi,
                                                float* __restrict__ out) {
    __shared__ __align__(16) char smX[4][8192];   // per-wave bf16 tile [16 rows][512B]
    const int tid  = threadIdx.x;
    const int lane = tid & 63;
    const int w    = tid >> 6;
    const int r15  = lane & 15;
    const int kg4  = lane >> 4;
    const int l31  = lane & 31;
    const int lh   = lane >> 5;
    const int R    = blockIdx.x * 64 + w * 16;    // wave's tile base row

    // (1) fully-coalesced nontemporal tile load: 16 instr x 1KB contiguous
    const f32x4* sre = (const f32x4*)(xr + (size_t)R * NDIM);
    const f32x4* sim = (const f32x4*)(xi + (size_t)R * NDIM);
    f32x4 G[16];
    #pragma unroll
    for (int p = 0; p < 8; ++p) G[p]     = __builtin_nontemporal_load(sre + p * 64 + lane);
    #pragma unroll
    for (int p = 0; p < 8; ++p) G[8 + p] = __builtin_nontemporal_load(sim + p * 64 + lane);

    // (2) convert + swizzled LDS stage (wave-private, no barrier)
    char* buf = &smX[w][0];
    #pragma unroll
    for (int p = 0; p < 8; ++p) {
        const int row = 2 * p + lh;
        const int swz = (row & 7) << 4;
        uint2 v;
        v.x = ((unsigned)f2bf(G[p][1]) << 16) | f2bf(G[p][0]);
        v.y = ((unsigned)f2bf(G[p][3]) << 16) | f2bf(G[p][2]);
        *(uint2*)(buf + row * 512 + ((l31 * 8) ^ swz)) = v;
        v.x = ((unsigned)f2bf(G[8 + p][1]) << 16) | f2bf(G[8 + p][0]);
        v.y = ((unsigned)f2bf(G[8 + p][3]) << 16) | f2bf(G[8 + p][2]);
        *(uint2*)(buf + row * 512 + 256 + ((l31 * 8) ^ swz)) = v;
    }

    // fragments: lane (kg4,r15) <- row r15, k = kc*32 + kg4*8 .. +7
    bf16x8 fx[8];
    const int rswz = (r15 & 7) << 4;
    #pragma unroll
    for (int kc = 0; kc < 8; ++kc) {
        const int off = (((kc & 3) * 64 + kg4 * 16) ^ rswz) + ((kc >= 4) ? 256 : 0);
        fx[kc] = *(const bf16x8*)(buf + r15 * 512 + off);
    }

    // (3) MFMA: A = table fragment (rows = n), B = x fragment (cols = b-row)
    const bf16x8* gT = (const bf16x8*)g_TB;
    const size_t orow = (size_t)(R + r15) * NDIM;
    #pragma unroll
    for (int nt = 0; nt < 8; ++nt) {
        f32x4 a0 = {0.f, 0.f, 0.f, 0.f};
        f32x4 a1 = {0.f, 0.f, 0.f, 0.f};
        #pragma unroll
        for (int kc = 0; kc < 4; ++kc)
            a0 = __builtin_amdgcn_mfma_f32_16x16x32_bf16(
                gT[(kc * 4 + kg4) * NDIM + nt * 16 + r15], fx[kc], a0, 0, 0, 0);
        #pragma unroll
        for (int kc = 4; kc < 8; ++kc)
            a1 = __builtin_amdgcn_mfma_f32_16x16x32_bf16(
                gT[(kc * 4 + kg4) * NDIM + nt * 16 + r15], fx[kc], a1, 0, 0, 0);
        const f32x4 s = a0 + a1;
        __builtin_nontemporal_store(s, (f32x4*)(out + orow + nt * 16 + kg4 * 4));
    }
}

// ---------------- K5b: complex-output fallback (bf16 re,im pairs) ----------------
__global__ __launch_bounds__(256) void cmatmul1(const float* __restrict__ xr,
                                                const float* __restrict__ xi,
                                                ushort2* __restrict__ outp) {
    const int lane  = threadIdx.x & 63;
    const int w     = threadIdx.x >> 6;
    const int btile = blockIdx.x * 64 + w * 16;
    const int r15   = lane & 15;
    const int kg4   = lane >> 4;
    const int bload = btile + r15;

    const bf16x8* Ur = (const bf16x8*)g_Ur;
    const bf16x8* Ui = (const bf16x8*)g_Ui;
    const float* xrp = xr + (size_t)bload * NDIM;
    const float* xip = xi + (size_t)bload * NDIM;

    bf16x8 ar[4], ai[4], ain[4];
    #pragma unroll
    for (int kc = 0; kc < 4; ++kc) {
        const int k0 = kc * 32 + kg4 * 8;
        float4 rlo = *(const float4*)(xrp + k0);
        float4 rhi = *(const float4*)(xrp + k0 + 4);
        float4 ilo = *(const float4*)(xip + k0);
        float4 ihi = *(const float4*)(xip + k0 + 4);
        bf16x8 vr, vi, vn;
        vr[0] = (short)f2bf(rlo.x); vr[1] = (short)f2bf(rlo.y);
        vr[2] = (short)f2bf(rlo.z); vr[3] = (short)f2bf(rlo.w);
        vr[4] = (short)f2bf(rhi.x); vr[5] = (short)f2bf(rhi.y);
        vr[6] = (short)f2bf(rhi.z); vr[7] = (short)f2bf(rhi.w);
        vi[0] = (short)f2bf(ilo.x); vi[1] = (short)f2bf(ilo.y);
        vi[2] = (short)f2bf(ilo.z); vi[3] = (short)f2bf(ilo.w);
        vi[4] = (short)f2bf(ihi.x); vi[5] = (short)f2bf(ihi.y);
        vi[6] = (short)f2bf(ihi.z); vi[7] = (short)f2bf(ihi.w);
        #pragma unroll
        for (int e = 0; e < 8; ++e) vn[e] = (short)(vi[e] ^ 0x8000);
        ar[kc] = vr; ai[kc] = vi; ain[kc] = vn;
    }

    #pragma unroll
    for (int nt = 0; nt < 8; ++nt) {
        f32x4 accR = {0.f, 0.f, 0.f, 0.f};
        f32x4 accI = {0.f, 0.f, 0.f, 0.f};
        #pragma unroll
        for (int kc = 0; kc < 4; ++kc) {
            const int kg = kc * 4 + kg4;
            bf16x8 br = Ur[kg * NDIM + nt * 16 + r15];
            bf16x8 bi = Ui[kg * NDIM + nt * 16 + r15];
            accR = __builtin_amdgcn_mfma_f32_16x16x32_bf16(ar[kc],  br, accR, 0, 0, 0);
            accR = __builtin_amdgcn_mfma_f32_16x16x32_bf16(ain[kc], bi, accR, 0, 0, 0);
            accI = __builtin_amdgcn_mfma_f32_16x16x32_bf16(ar[kc],  bi, accI, 0, 0, 0);
            accI = __builtin_amdgcn_mfma_f32_16x16x32_bf16(ai[kc],  br, accI, 0, 0, 0);
        }
        const int n    = nt * 16 + r15;
        const int brow = btile + kg4 * 4;
        #pragma unroll
        for (int r = 0; r < 4; ++r)
            outp[(size_t)(brow + r) * NDIM + n] = make_ushort2(f2bf(accR[r]), f2bf(accI[r]));
    }
}

extern "C" void kernel_launch(void* const* d_in, const int* in_sizes, int n_in,
                              void* d_out, int out_size, void* d_ws, size_t ws_size,
                              hipStream_t stream) {
    const float* xr  = (const float*)d_in[0];
    const float* xi  = (const float*)d_in[1];
    const float* mzi = (const float*)d_in[2];
    const float* oph = (const float*)d_in[3];

    build_scan<<<dim3(4, NCHUNK), dim3(256), 0, stream>>>(mzi);
    compose<<<dim3(NDIM, 8), dim3(128), 0, stream>>>(0);
    compose<<<dim3(NDIM, 4), dim3(128), 0, stream>>>(1);
    compose<<<dim3(NDIM, 2), dim3(128), 0, stream>>>(2);
    compose_final<<<dim3(NDIM), dim3(128), 0, stream>>>(oph);
    if (out_size == BDIM * NDIM) {
        cmatmul0<<<dim3(BDIM / 64), dim3(256), 0, stream>>>(xr, xi, (float*)d_out);
    } else {
        cmatmul1<<<dim3(BDIM / 64), dim3(256), 0, stream>>>(xr, xi, (ushort2*)d_out);
    }
}

// Round 10
// 108.832 us; speedup vs baseline: 1.1807x; 1.1807x over previous
//
#include <hip/hip_runtime.h>
#include <hip/hip_bf16.h>

#define NDIM 128
#define BDIM 131072
#define NMZI 8128                       // 128*127/2
#define NCHUNK 8                        // chunks of 16 whole sweeps
#define NJG 8                           // j-groups per block (scan groups)
#define NCOL 32                         // columns per block
#define NLOC 16                         // max local scan length = ceil(127/8)
static constexpr float CC = 0.70710678118654752440f;  // sqrt(0.5)

typedef __attribute__((ext_vector_type(8))) short bf16x8;
typedef __attribute__((ext_vector_type(4))) float f32x4;

// Static device scratch (d_ws size unknown -> don't touch it)
__device__ __align__(16) float2         g_V[NCHUNK * NDIM * NDIM];  // chunk partial unitaries
__device__ __align__(16) float2         g_W[4 * NDIM * NDIM];       // compose level 0 out
__device__ __align__(16) float2         g_Y[2 * NDIM * NDIM];       // compose level 1 out
// Packed K=256 table for real-output GEMM: kg2<16 -> Ur[k=kg2*8+e][n]; kg2>=16 -> -Ui
__device__ __align__(16) unsigned short g_TB[32 * NDIM * 8];        // 64 KB
// Separate tables for the (unlikely) complex-interleaved output mode
__device__ __align__(16) unsigned short g_Ur[16 * NDIM * 8];
__device__ __align__(16) unsigned short g_Ui[16 * NDIM * 8];

__device__ inline unsigned short f2bf(float f) {
    union { __hip_bfloat16 h; unsigned short u; } cv;
    cv.h = __float2bfloat16(f);
    return cv.u;
}

// ---------------- K2: build chunk partial unitaries (sweep-aligned affine-scan) ----
// grid (4 col-slabs, NCHUNK=8) x 256 threads = (8 groups x 32 cols).
// Chunk c applies sweeps [16c, 16c+16): each segment is one FULL sweep
// (i fixed, j = i+1..127). t_j = e_phi*U[j] independent; ri follows the
// affine recurrence ri_j = C*ri_{j-1} + C*t_j -> blocked scan (group-
// serial in regs, cross-group prefix via LDS). Phases double-buffered
// per sweep; sincos for sweep sw+1 computed in the shadow of sweep sw.
__global__ __launch_bounds__(256) void build_scan(const float* __restrict__ mzi) {
    __shared__ float2 Usm[NDIM][NCOL];        // 32 KB
    __shared__ float4 ph[2][NDIM];            // 4 KB: cur/next sweep phases
    __shared__ float4 comp[NJG][NCOL];        // 4 KB
    const int tid   = threadIdx.x;
    const int c     = tid & 31;
    const int g     = tid >> 5;
    const int col0  = blockIdx.x * NCOL;
    const int chunk = blockIdx.y;
    const int i0    = chunk * 16;

    for (int k = g; k < NDIM; k += NJG)
        Usm[k][c] = make_float2((k == col0 + c) ? 1.f : 0.f, 0.f);

    const float2* mzp = (const float2*)mzi;   // (theta, phi) pairs
    int base = 127 * i0 - (i0 * (i0 - 1)) / 2;   // first step of sweep i0
    {
        const int L0 = NDIM - 1 - i0;
        if (tid < L0) {
            const float2 mz = mzp[base + tid];
            float sp, cp, st, ct;
            sincosf(mz.y, &sp, &cp);
            sincosf(mz.x, &st, &ct);
            ph[0][tid] = make_float4(cp, sp, CC * ct, CC * st);
        }
    }
    __syncthreads();

    #pragma unroll 1
    for (int sw = 0; sw < 16; ++sw) {
        const int i = i0 + sw;
        const int L = NDIM - 1 - i;               // sweep length
        if (L <= 0) break;
        const int cur = sw & 1;

        // prefetch next sweep's (theta,phi) into regs (lands under this sweep)
        float2 mznext;
        const bool have = (sw < 15) && (tid < L - 1);
        if (have) mznext = mzp[base + L + tid];

        const float2 r0 = Usm[i][c];              // read BEFORE barrier
        const int nloc  = (L + NJG - 1) >> 3;
        const int myBeg = g * nloc;
        const int myN   = max(0, min(nloc, L - myBeg));

        // pass 1: t_j + local affine composite (A, B): r' = A*r + B
        float2 treg[NLOC];
        float2 qth[NLOC];
        float  A = 1.f;
        float2 Bc = make_float2(0.f, 0.f);
        #pragma unroll
        for (int kk = 0; kk < NLOC; ++kk) {
            if (kk < myN) {
                const int off = myBeg + kk;
                const float4 q  = ph[cur][off];
                const float2 rj = Usm[i + 1 + off][c];
                const float tr = fmaf(q.x, rj.x, -q.y * rj.y);
                const float ti = fmaf(q.x, rj.y,  q.y * rj.x);
                treg[kk] = make_float2(tr, ti);
                qth[kk]  = make_float2(q.z, q.w);
                Bc.x = CC * (Bc.x + tr);
                Bc.y = CC * (Bc.y + ti);
                A *= CC;
            }
        }
        comp[g][c] = make_float4(A, Bc.x, Bc.y, 0.f);
        __syncthreads();

        // exclusive prefix over groups < g, applied to r0
        float2 r = r0;
        for (int h = 0; h < g; ++h) {
            const float4 cm = comp[h][c];
            r.x = fmaf(cm.x, r.x, cm.y);
            r.y = fmaf(cm.x, r.y, cm.z);
        }

        // pass 2: new_j = C*e_th*(ri_{j-1} - t_j); advance r
        #pragma unroll
        for (int kk = 0; kk < NLOC; ++kk) {
            if (kk < myN) {
                const float2 t = treg[kk];
                const float2 q = qth[kk];
                const float dr = r.x - t.x, di = r.y - t.y;
                const float njx = fmaf(q.x, dr, -q.y * di);
                const float njy = fmaf(q.x, di,  q.y * dr);
                Usm[i + 1 + myBeg + kk][c] = make_float2(njx, njy);
                r.x = CC * (r.x + t.x);
                r.y = CC * (r.y + t.y);
            }
        }
        if (myN > 0 && (myBeg + myN == L))
            Usm[i][c] = r;

        // stage next sweep's phases (readers wait on the barrier below)
        if (have) {
            float sp, cp, st, ct;
            sincosf(mznext.y, &sp, &cp);
            sincosf(mznext.x, &st, &ct);
            ph[cur ^ 1][tid] = make_float4(cp, sp, CC * ct, CC * st);
        }
        __syncthreads();
        base += L;
    }

    float2* Vp = g_V + chunk * NDIM * NDIM;
    for (int k = g; k < NDIM; k += NJG)
        Vp[k * NDIM + col0 + c] = Usm[k][c];
}

// ---------------- K3: compose tree level ----------------
// level 0: W[p] = V[2p+1]*V[2p], p<4 ; level 1: Y[q] = W[2q+1]*W[2q], q<2
__global__ __launch_bounds__(128) void compose(int level) {
    const int p = blockIdx.y, n = blockIdx.x, m = threadIdx.x;
    const float2* A; const float2* B; float2* Cout;
    if (level == 0) {
        A = g_V + (2 * p + 1) * NDIM * NDIM;
        B = g_V + (2 * p) * NDIM * NDIM;
        Cout = g_W + p * NDIM * NDIM;
    } else {
        A = g_W + (2 * p + 1) * NDIM * NDIM;
        B = g_W + (2 * p) * NDIM * NDIM;
        Cout = g_Y + p * NDIM * NDIM;
    }
    __shared__ float2 arow[NDIM];
    arow[m] = A[n * NDIM + m];
    __syncthreads();
    float cr = 0.f, ci = 0.f;
    #pragma unroll 8
    for (int k = 0; k < NDIM; ++k) {
        const float2 b = B[k * NDIM + m];
        const float2 a = arow[k];
        cr = fmaf(a.x, b.x, fmaf(-a.y, b.y, cr));
        ci = fmaf(a.x, b.y, fmaf( a.y, b.x, ci));
    }
    Cout[n * NDIM + m] = make_float2(cr, ci);
}

// ---------------- K4: final compose U = Y1*Y0, diag, emit packed bf16 ----------------
__global__ __launch_bounds__(128) void compose_final(const float* __restrict__ oph) {
    const int n = blockIdx.x, m = threadIdx.x;
    const float2* A = g_Y + NDIM * NDIM;   // Y1 (left)
    const float2* B = g_Y;                 // Y0 (right)
    __shared__ float2 arow[NDIM];
    arow[m] = A[n * NDIM + m];
    __syncthreads();
    float cr = 0.f, ci = 0.f;
    #pragma unroll 8
    for (int k = 0; k < NDIM; ++k) {
        const float2 b = B[k * NDIM + m];
        const float2 a = arow[k];
        cr = fmaf(a.x, b.x, fmaf(-a.y, b.y, cr));
        ci = fmaf(a.x, b.y, fmaf( a.y, b.x, ci));
    }
    float ds, dc;
    sincosf(oph[n], &ds, &dc);
    const float vr = fmaf(cr, dc, -ci * ds);
    const float vi = fmaf(cr, ds,  ci * dc);
    const int kg = m >> 3, e = m & 7;
    g_TB[(kg * NDIM + n) * 8 + e]        = f2bf(vr);
    g_TB[((16 + kg) * NDIM + n) * 8 + e] = f2bf(-vi);
    g_Ur[(kg * NDIM + n) * 8 + e] = f2bf(vr);
    g_Ui[(kg * NDIM + n) * 8 + e] = f2bf(vi);
}

// ---------------- K5a: real-output GEMM (out_size == B*N, f32 real part) ----------------
// R9 structure (verified) + coalesced store path: MFMA results are stashed
// into the (dead) input LDS buffer (same XOR swizzle), then written as
// 8 x 1KB fully-contiguous NT stores (the wave's 16-row tile is one
// contiguous 8KB span of `out`). Per-wave DS ordering makes the buffer
// reuse safe without barriers.
__global__ __launch_bounds__(256) void cmatmul0(const float* __restrict__ xr,
                                                const float* __restrict__ xi,
                                                float* __restrict__ out) {
    __shared__ __align__(16) char smX[4][8192];   // per-wave tile buffer
    const int tid  = threadIdx.x;
    const int lane = tid & 63;
    const int w    = tid >> 6;
    const int r15  = lane & 15;
    const int kg4  = lane >> 4;
    const int l31  = lane & 31;
    const int lh   = lane >> 5;
    const int R    = blockIdx.x * 64 + w * 16;    // wave's tile base row

    // (1) fully-coalesced nontemporal tile load: 16 instr x 1KB contiguous
    const f32x4* sre = (const f32x4*)(xr + (size_t)R * NDIM);
    const f32x4* sim = (const f32x4*)(xi + (size_t)R * NDIM);
    f32x4 G[16];
    #pragma unroll
    for (int p = 0; p < 8; ++p) G[p]     = __builtin_nontemporal_load(sre + p * 64 + lane);
    #pragma unroll
    for (int p = 0; p < 8; ++p) G[8 + p] = __builtin_nontemporal_load(sim + p * 64 + lane);

    // (2) convert + swizzled LDS stage (wave-private, no barrier)
    char* buf = &smX[w][0];
    #pragma unroll
    for (int p = 0; p < 8; ++p) {
        const int row = 2 * p + lh;
        const int swz = (row & 7) << 4;
        uint2 v;
        v.x = ((unsigned)f2bf(G[p][1]) << 16) | f2bf(G[p][0]);
        v.y = ((unsigned)f2bf(G[p][3]) << 16) | f2bf(G[p][2]);
        *(uint2*)(buf + row * 512 + ((l31 * 8) ^ swz)) = v;
        v.x = ((unsigned)f2bf(G[8 + p][1]) << 16) | f2bf(G[8 + p][0]);
        v.y = ((unsigned)f2bf(G[8 + p][3]) << 16) | f2bf(G[8 + p][2]);
        *(uint2*)(buf + row * 512 + 256 + ((l31 * 8) ^ swz)) = v;
    }

    // fragments: lane (kg4,r15) <- row r15, k = kc*32 + kg4*8 .. +7
    bf16x8 fx[8];
    const int rswz = (r15 & 7) << 4;
    #pragma unroll
    for (int kc = 0; kc < 8; ++kc) {
        const int off = (((kc & 3) * 64 + kg4 * 16) ^ rswz) + ((kc >= 4) ? 256 : 0);
        fx[kc] = *(const bf16x8*)(buf + r15 * 512 + off);
    }

    // (3) MFMA; stash results into buf (input bytes are dead; DS in-order)
    const bf16x8* gT = (const bf16x8*)g_TB;
    #pragma unroll
    for (int nt = 0; nt < 8; ++nt) {
        f32x4 a0 = {0.f, 0.f, 0.f, 0.f};
        f32x4 a1 = {0.f, 0.f, 0.f, 0.f};
        #pragma unroll
        for (int kc = 0; kc < 4; ++kc)
            a0 = __builtin_amdgcn_mfma_f32_16x16x32_bf16(
                gT[(kc * 4 + kg4) * NDIM + nt * 16 + r15], fx[kc], a0, 0, 0, 0);
        #pragma unroll
        for (int kc = 4; kc < 8; ++kc)
            a1 = __builtin_amdgcn_mfma_f32_16x16x32_bf16(
                gT[(kc * 4 + kg4) * NDIM + nt * 16 + r15], fx[kc], a1, 0, 0, 0);
        const f32x4 s = a0 + a1;
        *(f32x4*)(buf + r15 * 512 + ((nt * 64 + kg4 * 16) ^ rswz)) = s;
    }

    // (4) contiguous NT stores: 8 instr x 1KB, tile = contiguous 8KB of out
    char* outp = (char*)(out + (size_t)R * NDIM);
    #pragma unroll
    for (int p = 0; p < 8; ++p) {
        const int bofs = p * 1024 + lane * 16;
        const int row  = bofs >> 9;
        const int colb = bofs & 511;
        const f32x4 v = *(const f32x4*)(buf + row * 512 + (colb ^ ((row & 7) << 4)));
        __builtin_nontemporal_store(v, (f32x4*)(outp + bofs));
    }
}

// ---------------- K5b: complex-output fallback (bf16 re,im pairs) ----------------
__global__ __launch_bounds__(256) void cmatmul1(const float* __restrict__ xr,
                                                const float* __restrict__ xi,
                                                ushort2* __restrict__ outp) {
    const int lane  = threadIdx.x & 63;
    const int w     = threadIdx.x >> 6;
    const int btile = blockIdx.x * 64 + w * 16;
    const int r15   = lane & 15;
    const int kg4   = lane >> 4;
    const int bload = btile + r15;

    const bf16x8* Ur = (const bf16x8*)g_Ur;
    const bf16x8* Ui = (const bf16x8*)g_Ui;
    const float* xrp = xr + (size_t)bload * NDIM;
    const float* xip = xi + (size_t)bload * NDIM;

    bf16x8 ar[4], ai[4], ain[4];
    #pragma unroll
    for (int kc = 0; kc < 4; ++kc) {
        const int k0 = kc * 32 + kg4 * 8;
        float4 rlo = *(const float4*)(xrp + k0);
        float4 rhi = *(const float4*)(xrp + k0 + 4);
        float4 ilo = *(const float4*)(xip + k0);
        float4 ihi = *(const float4*)(xip + k0 + 4);
        bf16x8 vr, vi, vn;
        vr[0] = (short)f2bf(rlo.x); vr[1] = (short)f2bf(rlo.y);
        vr[2] = (short)f2bf(rlo.z); vr[3] = (short)f2bf(rlo.w);
        vr[4] = (short)f2bf(rhi.x); vr[5] = (short)f2bf(rhi.y);
        vr[6] = (short)f2bf(rhi.z); vr[7] = (short)f2bf(rhi.w);
        vi[0] = (short)f2bf(ilo.x); vi[1] = (short)f2bf(ilo.y);
        vi[2] = (short)f2bf(ilo.z); vi[3] = (short)f2bf(ilo.w);
        vi[4] = (short)f2bf(ihi.x); vi[5] = (short)f2bf(ihi.y);
        vi[6] = (short)f2bf(ihi.z); vi[7] = (short)f2bf(ihi.w);
        #pragma unroll
        for (int e = 0; e < 8; ++e) vn[e] = (short)(vi[e] ^ 0x8000);
        ar[kc] = vr; ai[kc] = vi; ain[kc] = vn;
    }

    #pragma unroll
    for (int nt = 0; nt < 8; ++nt) {
        f32x4 accR = {0.f, 0.f, 0.f, 0.f};
        f32x4 accI = {0.f, 0.f, 0.f, 0.f};
        #pragma unroll
        for (int kc = 0; kc < 4; ++kc) {
            const int kg = kc * 4 + kg4;
            bf16x8 br = Ur[kg * NDIM + nt * 16 + r15];
            bf16x8 bi = Ui[kg * NDIM + nt * 16 + r15];
            accR = __builtin_amdgcn_mfma_f32_16x16x32_bf16(ar[kc],  br, accR, 0, 0, 0);
            accR = __builtin_amdgcn_mfma_f32_16x16x32_bf16(ain[kc], bi, accR, 0, 0, 0);
            accI = __builtin_amdgcn_mfma_f32_16x16x32_bf16(ar[kc],  bi, accI, 0, 0, 0);
            accI = __builtin_amdgcn_mfma_f32_16x16x32_bf16(ai[kc],  br, accI, 0, 0, 0);
        }
        const int n    = nt * 16 + r15;
        const int brow = btile + kg4 * 4;
        #pragma unroll
        for (int r = 0; r < 4; ++r)
            outp[(size_t)(brow + r) * NDIM + n] = make_ushort2(f2bf(accR[r]), f2bf(accI[r]));
    }
}

extern "C" void kernel_launch(void* const* d_in, const int* in_sizes, int n_in,
                              void* d_out, int out_size, void* d_ws, size_t ws_size,
                              hipStream_t stream) {
    const float* xr  = (const float*)d_in[0];
    const float* xi  = (const float*)d_in[1];
    const float* mzi = (const float*)d_in[2];
    const float* oph = (const float*)d_in[3];

    build_scan<<<dim3(4, NCHUNK), dim3(256), 0, stream>>>(mzi);
    compose<<<dim3(NDIM, 4), dim3(128), 0, stream>>>(0);
    compose<<<dim3(NDIM, 2), dim3(128), 0, stream>>>(1);
    compose_final<<<dim3(NDIM), dim3(128), 0, stream>>>(oph);
    if (out_size == BDIM * NDIM) {
        cmatmul0<<<dim3(BDIM / 64), dim3(256), 0, stream>>>(xr, xi, (float*)d_out);
    } else {
        cmatmul1<<<dim3(BDIM / 64), dim3(256), 0, stream>>>(xr, xi, (ushort2*)d_out);
    }
}